// Round 8
// baseline (2852.682 us; speedup 1.0000x reference)
//
#include <hip/hip_runtime.h>
#include <stdint.h>

typedef unsigned short ushort_t;

// Problem constants
#define NVOX   221184      // 2*48*48*48 voxels
#define NSTATE 7077888     // NVOX * 32 channels
// ws layout: stateA f32 | stateB f32 | wb f32 (biases) | wh u16 (bf16 frag tables) | flag
#define WB_CB   0          // conv_b[16]
#define WB_F0B  16         // fc0_b[128]
#define WB_TOT  160
// wh offsets (u16 units): pre-swizzled B-fragments, hi/lo split
#define CWH 0              // conv W frags [14 kst][64 lane][8]
#define CWL 7168
#define B0H 14336          // fc0 W frags [2 kst][8 nt][64][8]
#define B0L 22528
#define B1H 30720          // fc1 W frags [4 kt][2 n2][64][8]
#define B1L 34816
#define WH_TOT 38912       // u16 (= 19456 f32 slots)

// LDS (u16 units): halo xc | per-wave cv scratch | per-wave h scratch
#define XC0 0              // 600 rows x 20 (16 ch + pad4) bf16
#define CV0 12000          // 4 waves x 16 x 20
#define HB0 13280          // 4 waves x 16 x 36 (32 + pad4)
#define SH_TOT 15584

typedef __attribute__((ext_vector_type(8))) short   s8v;    // 8 bf16 (4 VGPRs)
typedef __attribute__((ext_vector_type(4))) float   f32x4;  // MFMA C/D
typedef __attribute__((ext_vector_type(4))) ushort_t u16x4; // 8B LDS chunk
union AF { s8v v; u16x4 h[2]; ushort_t u[8]; };
#define MFMA(a,b,c) __builtin_amdgcn_mfma_f32_16x16x32_bf16((a),(b),(c),0,0,0)

// ---------- bf16 helpers ----------
__host__ __device__ __forceinline__ float bf2f(ushort_t u) {
  union { uint32_t u; float f; } v; v.u = ((uint32_t)u) << 16; return v.f;
}
__device__ __forceinline__ ushort_t f2bf(float f) {  // RNE, finite values
  union { float f; uint32_t u; } v; v.f = f;
  uint32_t r = (v.u + 0x7FFFu + ((v.u >> 16) & 1u)) >> 16;
  return (ushort_t)r;
}
__device__ __forceinline__ float ldin(const void* p, int i, uint32_t bf) {
  return bf ? bf2f(((const ushort_t*)p)[i]) : ((const float*)p)[i];
}

// ---------- JAX Threefry-2x32 (verified bit-exact R3) ----------
__host__ __device__ __forceinline__ void tf2x32(uint32_t k0, uint32_t k1,
                                                uint32_t x0, uint32_t x1,
                                                uint32_t& o0, uint32_t& o1) {
  uint32_t ks2 = k0 ^ k1 ^ 0x1BD11BDAu;
#define TFR(r) { x0 += x1; x1 = (x1 << r) | (x1 >> (32 - r)); x1 ^= x0; }
  x0 += k0; x1 += k1;
  TFR(13) TFR(15) TFR(26) TFR(6)
  x0 += k1;  x1 += ks2 + 1u;
  TFR(17) TFR(29) TFR(16) TFR(24)
  x0 += ks2; x1 += k0 + 2u;
  TFR(13) TFR(15) TFR(26) TFR(6)
  x0 += k0;  x1 += k1 + 3u;
  TFR(17) TFR(29) TFR(16) TFR(24)
  x0 += k1;  x1 += ks2 + 4u;
  TFR(13) TFR(15) TFR(26) TFR(6)
  x0 += ks2; x1 += k0 + 5u;
#undef TFR
  o0 = x0; o1 = x1;
}
__device__ __forceinline__ float mask_val(uint32_t k0, uint32_t k1, uint32_t vi) {
  uint32_t r0, r1;
  tf2x32(k0, k1, 0u, vi, r0, r1);
  uint32_t bits = r0 ^ r1;
  return ((bits >> 9) > 0x400000u) ? 1.0f : 0.0f;
}

// ---------- dtype detector (verified R3: flags f32) ----------
__global__ void nca_detect(const uint32_t* __restrict__ x, uint32_t* __restrict__ flag) {
  __shared__ int cnt[256];
  uint32_t w = x[threadIdx.x];
  uint32_t e = (w >> 7) & 0xFFu;
  cnt[threadIdx.x] = (e >= 110u && e <= 140u) ? 1 : 0;
  __syncthreads();
  for (int s = 128; s > 0; s >>= 1) {
    if ((int)threadIdx.x < s) cnt[threadIdx.x] += cnt[threadIdx.x + s];
    __syncthreads();
  }
  if (threadIdx.x == 0) *flag = (cnt[0] >= 160) ? 1u : 0u;
}

// ---------- weight prep: biases f32 + pre-swizzled hi/lo bf16 B-fragments ----------
// Fragment convention (m89-verified): B[k][n] -> lane l=(q*16+nc) holds B[kbase+q*8+j][ntile*16+nc].
__global__ __launch_bounds__(256) void nca_prep(
    const void* __restrict__ cw, const void* __restrict__ cb,
    const void* __restrict__ f0w, const void* __restrict__ f0b,
    const void* __restrict__ f1w, float* __restrict__ wb,
    ushort_t* __restrict__ wh, const uint32_t* __restrict__ flagp) {
  uint32_t bf = *flagp;
  int e = blockIdx.x * 256 + threadIdx.x;
  if (e < 16) { wb[WB_CB + e] = ldin(cb, e, bf); return; }
  if (e < 144) { wb[WB_F0B + (e - 16)] = ldin(f0b, e - 16, bf); return; }
  int eh = e - 144;
  if (eh >= 19456) return;
  float v; int hidx, lidx;
  if (eh < 7168) {
    // conv: K = tap*16 + i (tap t = kx*9+ky*3+kz, R3-verified), N = o
    int kst = eh >> 9; int l = (eh >> 3) & 63; int j = eh & 7;
    int qq = l >> 4; int o = l & 15;
    int t = kst * 2 + (qq >> 1); int i = (qq & 1) * 8 + j;
    v = (t <= 26) ? ldin(cw, o * 432 + i * 27 + t, bf) : 0.0f;
    hidx = CWH + eh; lidx = CWL + eh;
  } else if (eh < 15360) {
    // fc0: B[k=0..47 (pad 64)][n=0..127], fc0_w[n][k]
    int r = eh - 7168;
    int kst = r >> 12; int rem = r & 4095;
    int nt = rem >> 9; int l = (rem >> 3) & 63; int j = rem & 7;
    int qq = l >> 4; int n = nt * 16 + (l & 15);
    int k = kst * 32 + qq * 8 + j;
    v = (k < 48) ? ldin(f0w, n * 48 + k, bf) : 0.0f;
    hidx = B0H + r; lidx = B0L + r;
  } else {
    // fc1: B[k=0..127][c=0..31], fc1_w[c][k]
    int r = eh - 15360;
    int kt = r >> 10; int rem = r & 1023;
    int n2 = rem >> 9; int l = (rem >> 3) & 63; int j = rem & 7;
    int qq = l >> 4; int c = n2 * 16 + (l & 15);
    int k = kt * 32 + qq * 8 + j;
    v = ldin(f1w, c * 128 + k, bf);
    hidx = B1H + r; lidx = B1L + r;
  }
  ushort_t hi = f2bf(v);
  float hf = bf2f(hi);
  ushort_t lo = f2bf(v - hf);
  wh[hidx] = hi; wh[lidx] = lo;
}

// ---------- init: state ch0..15 = x, ch16..31 = 0 ----------
__global__ __launch_bounds__(256) void nca_init(const void* __restrict__ x,
                                                float* __restrict__ st,
                                                const uint32_t* __restrict__ flagp) {
  uint32_t bf = *flagp;
  int gid = blockIdx.x * 256 + threadIdx.x;
  float v[32];
#pragma unroll
  for (int c = 0; c < 16; c++) v[c] = ldin(x, gid * 16 + c, bf);
#pragma unroll
  for (int c = 16; c < 32; c++) v[c] = 0.0f;
  float* po = st + (size_t)gid * 32;
#pragma unroll
  for (int c = 0; c < 32; c += 4)
    *(float4*)(po + c) = make_float4(v[c], v[c + 1], v[c + 2], v[c + 3]);
}

// ---------- one NCA step, full-MFMA ----------
// Block = 8x8x4 tile (256 vox, 4 waves). Per wave: 4 m-tiles of 16 voxels.
// conv: D[m][o] = sum_k A[m][k=tap*16+i] W[k][o], 14 K32-steps, A gathered
// from LDS-staged bf16 halo (10x10x6). fc0: K=48 (2 K-steps, k>=48 zero).
// fc1: K=128 (4 K-steps), h via per-wave LDS D->A re-layout.
// Weights 2-term hi/lo split (kills systematic bf16 weight error);
// activations single bf16 RNE (random-walk error, budgeted).
__global__ __launch_bounds__(256, 3) void nca_step(
    const float* __restrict__ sin, float* __restrict__ sout,
    const float* __restrict__ wb, const ushort_t* __restrict__ wh,
    uint32_t k0, uint32_t k1) {
  __shared__ ushort_t SH[SH_TOT];
  __shared__ float maskb[256];

  int bx = blockIdx.x;
  int tx = bx % 6;  int r0i = bx / 6;
  int ty = r0i % 6; int r1i = r0i / 6;
  int tz = r1i % 12; int b = r1i / 12;
  int tid = threadIdx.x;

  // ---- Phase A: stage halo xc as bf16; compute masks ----
  for (int hr = tid; hr < 600; hr += 256) {
    int hz = hr / 100, rm = hr % 100, hy = rm / 10, hx = rm % 10;
    int gd = tz * 4 + hz - 1; gd = (gd < 0) ? 1 : ((gd > 47) ? 46 : gd);
    int gh = ty * 8 + hy - 1; gh = (gh < 0) ? 1 : ((gh > 47) ? 46 : gh);
    int gw = tx * 8 + hx - 1; gw = (gw < 0) ? 1 : ((gw > 47) ? 46 : gw);
    const float* p = sin + ((((size_t)b * 48 + gd) * 48 + gh) * 48 + gw) * 32;
    ushort_t* dst = SH + XC0 + hr * 20;
#pragma unroll
    for (int c = 0; c < 16; c += 4) {
      float4 v = *(const float4*)(p + c);
      dst[c + 0] = f2bf(v.x); dst[c + 1] = f2bf(v.y);
      dst[c + 2] = f2bf(v.z); dst[c + 3] = f2bf(v.w);
    }
  }
  {
    int v = tid; int x = v & 7, y = (v >> 3) & 7, z = v >> 6;
    int gid = ((b * 48 + tz * 4 + z) * 48 + ty * 8 + y) * 48 + tx * 8 + x;
    maskb[v] = mask_val(k0, k1, (uint32_t)gid);
  }
  __syncthreads();

  // ---- Phase B: MFMA pipeline ----
  int lane = tid & 63, wave = tid >> 6;
  int q = lane >> 4, mcol = lane & 15;
  int qh = q >> 1, ql = q & 1;
  float cbias = wb[WB_CB + mcol];
  const int cvbase = CV0 + wave * 320;
  const int hbbase = HB0 + wave * 576;

  for (int mm = 0; mm < 4; mm++) {
    int mt = wave * 4 + mm;
    int v = mt * 16 + mcol;                 // this lane's A-row voxel
    int x = v & 7, y = (v >> 3) & 7, z = v >> 6;
    int hbase = (z + 1) * 100 + (y + 1) * 10 + (x + 1);
    size_t gidv = ((size_t)(b * 48 + tz * 4 + z) * 48 + ty * 8 + y) * 48 + tx * 8 + x;

    // conv: 14 K-steps x 2 (hi/lo W)
    f32x4 cv = {0.f, 0.f, 0.f, 0.f};
    for (int kst = 0; kst < 14; kst++) {
      int t = kst * 2 + qh; if (t > 26) t = 26;   // kst=13,qh=1: B frags are zero
      int kz = t % 3, kxx = t / 9, kyy = (t / 3) % 3;
      int hr = hbase + (kz - 1) * 100 + (kxx - 1) * 10 + (kyy - 1);
      int off = hr * 20 + ql * 8;
      AF a;
      a.h[0] = *(const u16x4*)(SH + off);
      a.h[1] = *(const u16x4*)(SH + off + 4);
      s8v bh = *(const s8v*)(wh + CWH + (size_t)(kst * 64 + lane) * 8);
      s8v bl = *(const s8v*)(wh + CWL + (size_t)(kst * 64 + lane) * 8);
      cv = MFMA(a.v, bh, cv);
      cv = MFMA(a.v, bl, cv);
    }
    // bias + D->A re-layout of cv through per-wave LDS scratch
    {
      ushort_t* cwp = SH + cvbase;
#pragma unroll
      for (int r = 0; r < 4; r++)
        cwp[(q * 4 + r) * 20 + mcol] = f2bf(cv[r] + cbias);
    }
    __syncthreads();

    // fc0 A-frags: kst0 = [xc | cv], kst1 = [xm | zeros]
    AF a0k0, a0k1;
    {
      int off0 = (q < 2) ? (hbase * 20 + q * 8)
                         : (cvbase + mcol * 20 + (q - 2) * 8);
      a0k0.h[0] = *(const u16x4*)(SH + off0);
      a0k0.h[1] = *(const u16x4*)(SH + off0 + 4);
      if (q < 2) {
        const float* pm = sin + gidv * 32 + 16 + q * 8;
        float4 m0 = *(const float4*)(pm);
        float4 m1 = *(const float4*)(pm + 4);
        a0k1.u[0] = f2bf(m0.x); a0k1.u[1] = f2bf(m0.y);
        a0k1.u[2] = f2bf(m0.z); a0k1.u[3] = f2bf(m0.w);
        a0k1.u[4] = f2bf(m1.x); a0k1.u[5] = f2bf(m1.y);
        a0k1.u[6] = f2bf(m1.z); a0k1.u[7] = f2bf(m1.w);
      } else {
#pragma unroll
        for (int j = 0; j < 8; j++) a0k1.u[j] = 0;
      }
    }

    // fc0 (8 n-tiles) interleaved with fc1 (4 K-steps of 2 n-tiles each)
    f32x4 dxa[2];
    dxa[0] = (f32x4){0.f, 0.f, 0.f, 0.f};
    dxa[1] = (f32x4){0.f, 0.f, 0.f, 0.f};
    for (int kt = 0; kt < 4; kt++) {
#pragma unroll
      for (int t2 = 0; t2 < 2; t2++) {
        int nt = kt * 2 + t2;
        float hb0 = wb[WB_F0B + nt * 16 + mcol];
        f32x4 acc = {hb0, hb0, hb0, hb0};
        s8v b00h = *(const s8v*)(wh + B0H + (size_t)((0 * 8 + nt) * 64 + lane) * 8);
        s8v b00l = *(const s8v*)(wh + B0L + (size_t)((0 * 8 + nt) * 64 + lane) * 8);
        s8v b01h = *(const s8v*)(wh + B0H + (size_t)((1 * 8 + nt) * 64 + lane) * 8);
        s8v b01l = *(const s8v*)(wh + B0L + (size_t)((1 * 8 + nt) * 64 + lane) * 8);
        acc = MFMA(a0k0.v, b00h, acc);
        acc = MFMA(a0k0.v, b00l, acc);
        acc = MFMA(a0k1.v, b01h, acc);
        acc = MFMA(a0k1.v, b01l, acc);
        ushort_t* hw = SH + hbbase;
#pragma unroll
        for (int r = 0; r < 4; r++)
          hw[(q * 4 + r) * 36 + t2 * 16 + mcol] = f2bf(fmaxf(acc[r], 0.f));
      }
      __syncthreads();
      AF a2;
      {
        int off = hbbase + mcol * 36 + q * 8;
        a2.h[0] = *(const u16x4*)(SH + off);
        a2.h[1] = *(const u16x4*)(SH + off + 4);
      }
#pragma unroll
      for (int n2 = 0; n2 < 2; n2++) {
        s8v b1h = *(const s8v*)(wh + B1H + (size_t)((kt * 2 + n2) * 64 + lane) * 8);
        s8v b1l = *(const s8v*)(wh + B1L + (size_t)((kt * 2 + n2) * 64 + lane) * 8);
        dxa[n2] = MFMA(a2.v, b1h, dxa[n2]);
        dxa[n2] = MFMA(a2.v, b1l, dxa[n2]);
      }
      __syncthreads();
    }

    // epilogue: residual + mask, channel 0 frozen
#pragma unroll
    for (int r = 0; r < 4; r++) {
      int vv = mt * 16 + q * 4 + r;
      int xx = vv & 7, yy = (vv >> 3) & 7, zz = vv >> 6;
      size_t gg = ((size_t)(b * 48 + tz * 4 + zz) * 48 + ty * 8 + yy) * 48 + tx * 8 + xx;
      float mk = maskb[vv];
#pragma unroll
      for (int n2 = 0; n2 < 2; n2++) {
        int c = n2 * 16 + mcol;
        float oldv = sin[gg * 32 + c];
        float outv = (c == 0) ? oldv : fmaf(dxa[n2][r], mk, oldv);
        sout[gg * 32 + c] = outv;
      }
    }
  }
}

// ---------- final f32 state -> output (dtype per flag) ----------
__global__ __launch_bounds__(256) void nca_out(const float* __restrict__ st,
                                               void* __restrict__ out,
                                               const uint32_t* __restrict__ flagp) {
  uint32_t bf = *flagp;
  int gid = blockIdx.x * 256 + threadIdx.x;
  float4 v = *(const float4*)(st + (size_t)gid * 4);
  if (bf) {
    ushort4 u;
    u.x = f2bf(v.x); u.y = f2bf(v.y); u.z = f2bf(v.z); u.w = f2bf(v.w);
    *(ushort4*)((ushort_t*)out + (size_t)gid * 4) = u;
  } else {
    *(float4*)((float*)out + (size_t)gid * 4) = v;
  }
}

extern "C" void kernel_launch(void* const* d_in, const int* in_sizes, int n_in,
                              void* d_out, int out_size, void* d_ws, size_t ws_size,
                              hipStream_t stream) {
  float* ws = (float*)d_ws;
  float* sA = ws;
  float* sB = ws + NSTATE;
  float* wb = ws + 2 * NSTATE;
  ushort_t* wh = (ushort_t*)(ws + 2 * NSTATE + WB_TOT);
  uint32_t* flag = (uint32_t*)(ws + 2 * NSTATE + WB_TOT + WH_TOT / 2);

  nca_detect<<<1, 256, 0, stream>>>((const uint32_t*)d_in[0], flag);
  nca_prep<<<77, 256, 0, stream>>>(d_in[1], d_in[2], d_in[3], d_in[4], d_in[5],
                                   wb, wh, flag);
  nca_init<<<NVOX / 256, 256, 0, stream>>>(d_in[0], sA, flag);

  float* src = sA;
  float* dst = sB;
  for (int s = 0; s < 10; s++) {
    uint32_t o0, o1;
    tf2x32(0u, 42u, 0u, (uint32_t)s, o0, o1);   // folded step key, host-side
    nca_step<<<864, 256, 0, stream>>>(src, dst, wb, wh, o0, o1);
    float* tmp = src; src = dst; dst = tmp;
  }
  nca_out<<<NSTATE / 4 / 256, 256, 0, stream>>>(src, d_out, flag);
}

// Round 9
// 494.858 us; speedup vs baseline: 5.7646x; 5.7646x over previous
//
#include <hip/hip_runtime.h>
#include <stdint.h>

typedef unsigned short ushort_t;

// Problem constants
#define NVOX   221184      // 2*48*48*48 voxels
#define NSTATE 7077888     // NVOX * 32 channels
// ws layout: stateA f32 | stateB f32 | wb f32 (biases) | wh u16 (bf16 frag tables) | flag
#define WB_CB   0          // conv_b[16]
#define WB_F0B  16         // fc0_b[128]
#define WB_TOT  160
// wh offsets (u16 units): pre-swizzled hi/lo bf16 fragment tables (R8-verified)
#define CWH 0              // conv W frags [14 kst][64 lane][8]
#define CWL 7168
#define B0H 14336          // fc0 W frags [2 kst][8 nt][64][8]
#define B0L 22528
#define B1H 30720          // fc1 W frags [4 kt][2 ct][64][8]
#define B1L 34816
#define WH_TOT 38912       // u16

// LDS (u16 units)
#define XC0   0            // halo xc: 600 rows x 24 (16 ch + pad8, 48B rows for b128 align)
#define CVS0  14400        // cv scratch: 4 waves x 16 x 24
#define HSB0  15936        // h scratch: 4 waves x 4 mm x 16 x 40 (80B rows)
#define SH_TOT 26176       // 52.4 KB -> 2 blocks/CU with maskb

typedef __attribute__((ext_vector_type(8))) short    s8v;    // 8 bf16 (4 VGPRs)
typedef __attribute__((ext_vector_type(4))) float    f32x4;  // MFMA C/D
typedef __attribute__((ext_vector_type(4))) ushort_t u16x4;  // 8B LDS chunk
union AF { s8v v; u16x4 h[2]; ushort_t u[8]; };
#define MFMA(a,b,c) __builtin_amdgcn_mfma_f32_16x16x32_bf16((a),(b),(c),0,0,0)
// compiler-only memory barrier: same-wave DS ops are HW-in-order; this stops reordering
#define CBAR() __asm__ volatile("" ::: "memory")

// ---------- bf16 helpers ----------
__host__ __device__ __forceinline__ float bf2f(ushort_t u) {
  union { uint32_t u; float f; } v; v.u = ((uint32_t)u) << 16; return v.f;
}
__device__ __forceinline__ ushort_t f2bf(float f) {  // RNE, finite values
  union { float f; uint32_t u; } v; v.f = f;
  uint32_t r = (v.u + 0x7FFFu + ((v.u >> 16) & 1u)) >> 16;
  return (ushort_t)r;
}
__device__ __forceinline__ float ldin(const void* p, int i, uint32_t bf) {
  return bf ? bf2f(((const ushort_t*)p)[i]) : ((const float*)p)[i];
}

// ---------- JAX Threefry-2x32 (verified bit-exact R3) ----------
__host__ __device__ __forceinline__ void tf2x32(uint32_t k0, uint32_t k1,
                                                uint32_t x0, uint32_t x1,
                                                uint32_t& o0, uint32_t& o1) {
  uint32_t ks2 = k0 ^ k1 ^ 0x1BD11BDAu;
#define TFR(r) { x0 += x1; x1 = (x1 << r) | (x1 >> (32 - r)); x1 ^= x0; }
  x0 += k0; x1 += k1;
  TFR(13) TFR(15) TFR(26) TFR(6)
  x0 += k1;  x1 += ks2 + 1u;
  TFR(17) TFR(29) TFR(16) TFR(24)
  x0 += ks2; x1 += k0 + 2u;
  TFR(13) TFR(15) TFR(26) TFR(6)
  x0 += k0;  x1 += k1 + 3u;
  TFR(17) TFR(29) TFR(16) TFR(24)
  x0 += k1;  x1 += ks2 + 4u;
  TFR(13) TFR(15) TFR(26) TFR(6)
  x0 += ks2; x1 += k0 + 5u;
#undef TFR
  o0 = x0; o1 = x1;
}
__device__ __forceinline__ float mask_val(uint32_t k0, uint32_t k1, uint32_t vi) {
  uint32_t r0, r1;
  tf2x32(k0, k1, 0u, vi, r0, r1);
  uint32_t bits = r0 ^ r1;
  return ((bits >> 9) > 0x400000u) ? 1.0f : 0.0f;
}

// ---------- dtype detector (verified R3: flags f32) ----------
__global__ void nca_detect(const uint32_t* __restrict__ x, uint32_t* __restrict__ flag) {
  __shared__ int cnt[256];
  uint32_t w = x[threadIdx.x];
  uint32_t e = (w >> 7) & 0xFFu;
  cnt[threadIdx.x] = (e >= 110u && e <= 140u) ? 1 : 0;
  __syncthreads();
  for (int s = 128; s > 0; s >>= 1) {
    if ((int)threadIdx.x < s) cnt[threadIdx.x] += cnt[threadIdx.x + s];
    __syncthreads();
  }
  if (threadIdx.x == 0) *flag = (cnt[0] >= 160) ? 1u : 0u;
}

// ---------- weight prep (VERBATIM from R8 — verified by its pass) ----------
__global__ __launch_bounds__(256) void nca_prep(
    const void* __restrict__ cw, const void* __restrict__ cb,
    const void* __restrict__ f0w, const void* __restrict__ f0b,
    const void* __restrict__ f1w, float* __restrict__ wb,
    ushort_t* __restrict__ wh, const uint32_t* __restrict__ flagp) {
  uint32_t bf = *flagp;
  int e = blockIdx.x * 256 + threadIdx.x;
  if (e < 16) { wb[WB_CB + e] = ldin(cb, e, bf); return; }
  if (e < 144) { wb[WB_F0B + (e - 16)] = ldin(f0b, e - 16, bf); return; }
  int eh = e - 144;
  if (eh >= 19456) return;
  float v; int hidx, lidx;
  if (eh < 7168) {
    int kst = eh >> 9; int l = (eh >> 3) & 63; int j = eh & 7;
    int qq = l >> 4; int o = l & 15;
    int t = kst * 2 + (qq >> 1); int i = (qq & 1) * 8 + j;
    v = (t <= 26) ? ldin(cw, o * 432 + i * 27 + t, bf) : 0.0f;
    hidx = CWH + eh; lidx = CWL + eh;
  } else if (eh < 15360) {
    int r = eh - 7168;
    int kst = r >> 12; int rem = r & 4095;
    int nt = rem >> 9; int l = (rem >> 3) & 63; int j = rem & 7;
    int qq = l >> 4; int n = nt * 16 + (l & 15);
    int k = kst * 32 + qq * 8 + j;
    v = (k < 48) ? ldin(f0w, n * 48 + k, bf) : 0.0f;
    hidx = B0H + r; lidx = B0L + r;
  } else {
    int r = eh - 15360;
    int kt = r >> 10; int rem = r & 1023;
    int n2 = rem >> 9; int l = (rem >> 3) & 63; int j = rem & 7;
    int qq = l >> 4; int c = n2 * 16 + (l & 15);
    int k = kt * 32 + qq * 8 + j;
    v = ldin(f1w, c * 128 + k, bf);
    hidx = B1H + r; lidx = B1L + r;
  }
  ushort_t hi = f2bf(v);
  float hf = bf2f(hi);
  ushort_t lo = f2bf(v - hf);
  wh[hidx] = hi; wh[lidx] = lo;
}

// ---------- init: state ch0..15 = x, ch16..31 = 0 ----------
__global__ __launch_bounds__(256) void nca_init(const void* __restrict__ x,
                                                float* __restrict__ st,
                                                const uint32_t* __restrict__ flagp) {
  uint32_t bf = *flagp;
  int gid = blockIdx.x * 256 + threadIdx.x;
  float v[32];
#pragma unroll
  for (int c = 0; c < 16; c++) v[c] = ldin(x, gid * 16 + c, bf);
#pragma unroll
  for (int c = 16; c < 32; c++) v[c] = 0.0f;
  float* po = st + (size_t)gid * 32;
#pragma unroll
  for (int c = 0; c < 32; c += 4)
    *(float4*)(po + c) = make_float4(v[c], v[c + 1], v[c + 2], v[c + 3]);
}

// ---------- one NCA step, MFMA v2: transposed GEMMs, weights loop-hoisted ----------
// All D^T: D rows = out-channels, cols = voxels (lane&15). Consequences:
//  * epilogue is coalesced float4 per lane (voxel = col, regs = 4 contiguous ch)
//  * conv->fc0 and fc0->fc1 re-layouts are contiguous b64 writes / b128 reads
//  * weight frag tables are IDENTICAL to R8's (A/B frags share lane layout)
// One __syncthreads total; per-wave LDS scratch relies on same-wave DS ordering.
__global__ __launch_bounds__(256, 2) void nca_step(
    const float* __restrict__ sin, float* __restrict__ sout,
    const float* __restrict__ wb, const ushort_t* __restrict__ wh,
    uint32_t k0, uint32_t k1) {
  __shared__ ushort_t SH[SH_TOT];
  __shared__ float maskb[256];

  int bx = blockIdx.x;
  int tx = bx % 6;  int r0i = bx / 6;
  int ty = r0i % 6; int r1i = r0i / 6;
  int tz = r1i % 12; int b = r1i / 12;
  int tid = threadIdx.x;

  // ---- Phase A: halo xc -> LDS bf16 (48B rows); masks ----
  for (int hr = tid; hr < 600; hr += 256) {
    int hz = hr / 100, rm = hr % 100, hy = rm / 10, hx = rm % 10;
    int gd = tz * 4 + hz - 1; gd = (gd < 0) ? 1 : ((gd > 47) ? 46 : gd);
    int gh = ty * 8 + hy - 1; gh = (gh < 0) ? 1 : ((gh > 47) ? 46 : gh);
    int gw = tx * 8 + hx - 1; gw = (gw < 0) ? 1 : ((gw > 47) ? 46 : gw);
    const float* p = sin + ((((size_t)b * 48 + gd) * 48 + gh) * 48 + gw) * 32;
    ushort_t* dst = SH + XC0 + hr * 24;
#pragma unroll
    for (int c = 0; c < 16; c += 4) {
      float4 v = *(const float4*)(p + c);
      u16x4 t;
      t[0] = f2bf(v.x); t[1] = f2bf(v.y); t[2] = f2bf(v.z); t[3] = f2bf(v.w);
      *(u16x4*)(dst + c) = t;
    }
  }
  {
    int v = tid; int x = v & 7, y = (v >> 3) & 7, z = v >> 6;
    int gid = ((b * 48 + tz * 4 + z) * 48 + ty * 8 + y) * 48 + tx * 8 + x;
    maskb[v] = mask_val(k0, k1, (uint32_t)gid);
  }
  __syncthreads();   // the ONLY block barrier

  int lane = tid & 63, wave = tid >> 6;
  int q = lane >> 4, mcol = lane & 15;
  int ql = q & 1, qh = q >> 1;
  const int cvs = CVS0 + wave * 384;
  const int hsb = HSB0 + wave * 2560;

  // lane's column-voxel geometry per m-tile
  int hb[4]; int gvx[4];
#pragma unroll
  for (int mm = 0; mm < 4; mm++) {
    int v = (wave * 4 + mm) * 16 + mcol;
    int x = v & 7, y = (v >> 3) & 7, z = v >> 6;
    hb[mm] = (z + 1) * 100 + (y + 1) * 10 + (x + 1);
    gvx[mm] = ((b * 48 + tz * 4 + z) * 48 + ty * 8 + y) * 48 + tx * 8 + x;
  }

  // ---- conv: cv^T[o][v], kst outer (weights once), mm inner (4 indep chains) ----
  f32x4 acc[4];
#pragma unroll
  for (int mm = 0; mm < 4; mm++) acc[mm] = (f32x4){0.f, 0.f, 0.f, 0.f};
  for (int kst = 0; kst < 14; kst++) {
    int t = kst * 2 + qh; if (t > 26) t = 26;     // padded taps hit zero weights
    int kz = t % 3, kxx = t / 9, kyy = (t / 3) % 3;
    int roff = (kz - 1) * 100 + (kxx - 1) * 10 + (kyy - 1);
    s8v bh = *(const s8v*)(wh + CWH + (size_t)(kst * 64 + lane) * 8);
    s8v bl = *(const s8v*)(wh + CWL + (size_t)(kst * 64 + lane) * 8);
#pragma unroll
    for (int mm = 0; mm < 4; mm++) {
      s8v a = *(const s8v*)(SH + (hb[mm] + roff) * 24 + ql * 8);
      acc[mm] = MFMA(bh, a, acc[mm]);
      acc[mm] = MFMA(bl, a, acc[mm]);
    }
  }

  // ---- din B-frags: k0 = [xc(0..15) | cv(16..31)], k1 = [xm(32..47) | 0] ----
  float4 cb4 = *(const float4*)(wb + WB_CB + q * 4);
  AF fk0[4], fk1[4];
#pragma unroll
  for (int mm = 0; mm < 4; mm++) {
    u16x4 pk;
    pk[0] = f2bf(acc[mm][0] + cb4.x);
    pk[1] = f2bf(acc[mm][1] + cb4.y);
    pk[2] = f2bf(acc[mm][2] + cb4.z);
    pk[3] = f2bf(acc[mm][3] + cb4.w);
    *(u16x4*)(SH + cvs + mcol * 24 + q * 4) = pk;   // cv^T -> [voxel][o] rows
    CBAR();
    int off0 = (q < 2) ? (hb[mm] * 24 + q * 8)                 // xc: center-tap halo row
                       : (cvs + mcol * 24 + (q - 2) * 8);      // cv
    fk0[mm].v = *(const s8v*)(SH + off0);
    CBAR();                                          // keep next mm's write after read
    if (q < 2) {
      const float* pm = sin + (size_t)gvx[mm] * 32 + 16 + q * 8;
      float4 m0 = *(const float4*)(pm);
      float4 m1 = *(const float4*)(pm + 4);
      fk1[mm].u[0] = f2bf(m0.x); fk1[mm].u[1] = f2bf(m0.y);
      fk1[mm].u[2] = f2bf(m0.z); fk1[mm].u[3] = f2bf(m0.w);
      fk1[mm].u[4] = f2bf(m1.x); fk1[mm].u[5] = f2bf(m1.y);
      fk1[mm].u[6] = f2bf(m1.z); fk1[mm].u[7] = f2bf(m1.w);
    } else {
#pragma unroll
      for (int j = 0; j < 8; j++) fk1[mm].u[j] = 0;
    }
  }

  // ---- fc0 (h^T) + fc1 (dx^T) interleaved: kt outer, mm inner ----
  f32x4 dxa[4][2];
#pragma unroll
  for (int mm = 0; mm < 4; mm++) {
    dxa[mm][0] = (f32x4){0.f, 0.f, 0.f, 0.f};
    dxa[mm][1] = (f32x4){0.f, 0.f, 0.f, 0.f};
  }
  for (int kt = 0; kt < 4; kt++) {
#pragma unroll
    for (int t2 = 0; t2 < 2; t2++) {
      int nt = kt * 2 + t2;
      float4 b4 = *(const float4*)(wb + WB_F0B + nt * 16 + q * 4);
      s8v w00h = *(const s8v*)(wh + B0H + (size_t)((nt) * 64 + lane) * 8);
      s8v w00l = *(const s8v*)(wh + B0L + (size_t)((nt) * 64 + lane) * 8);
      s8v w01h = *(const s8v*)(wh + B0H + (size_t)((8 + nt) * 64 + lane) * 8);
      s8v w01l = *(const s8v*)(wh + B0L + (size_t)((8 + nt) * 64 + lane) * 8);
#pragma unroll
      for (int mm = 0; mm < 4; mm++) {
        f32x4 a0 = (f32x4){b4.x, b4.y, b4.z, b4.w};
        a0 = MFMA(w00h, fk0[mm].v, a0);
        a0 = MFMA(w00l, fk0[mm].v, a0);
        a0 = MFMA(w01h, fk1[mm].v, a0);
        a0 = MFMA(w01l, fk1[mm].v, a0);
        u16x4 pk;
        pk[0] = f2bf(fmaxf(a0[0], 0.f));
        pk[1] = f2bf(fmaxf(a0[1], 0.f));
        pk[2] = f2bf(fmaxf(a0[2], 0.f));
        pk[3] = f2bf(fmaxf(a0[3], 0.f));
        *(u16x4*)(SH + hsb + mm * 640 + mcol * 40 + t2 * 16 + q * 4) = pk;
      }
    }
    CBAR();
    s8v w1h0 = *(const s8v*)(wh + B1H + (size_t)((kt * 2 + 0) * 64 + lane) * 8);
    s8v w1l0 = *(const s8v*)(wh + B1L + (size_t)((kt * 2 + 0) * 64 + lane) * 8);
    s8v w1h1 = *(const s8v*)(wh + B1H + (size_t)((kt * 2 + 1) * 64 + lane) * 8);
    s8v w1l1 = *(const s8v*)(wh + B1L + (size_t)((kt * 2 + 1) * 64 + lane) * 8);
#pragma unroll
    for (int mm = 0; mm < 4; mm++) {
      s8v a2 = *(const s8v*)(SH + hsb + mm * 640 + mcol * 40 + q * 8);
      dxa[mm][0] = MFMA(w1h0, a2, dxa[mm][0]);
      dxa[mm][0] = MFMA(w1l0, a2, dxa[mm][0]);
      dxa[mm][1] = MFMA(w1h1, a2, dxa[mm][1]);
      dxa[mm][1] = MFMA(w1l1, a2, dxa[mm][1]);
    }
    CBAR();
  }

  // ---- epilogue: coalesced float4 residual update; channel 0 frozen ----
#pragma unroll
  for (int mm = 0; mm < 4; mm++) {
    float mk = maskb[wave * 64 + mm * 16 + mcol];
#pragma unroll
    for (int ct = 0; ct < 2; ct++) {
      size_t base = (size_t)gvx[mm] * 32 + ct * 16 + q * 4;
      float4 od = *(const float4*)(sin + base);
      float4 nv;
      nv.x = fmaf(dxa[mm][ct][0], mk, od.x);
      nv.y = fmaf(dxa[mm][ct][1], mk, od.y);
      nv.z = fmaf(dxa[mm][ct][2], mk, od.z);
      nv.w = fmaf(dxa[mm][ct][3], mk, od.w);
      if (ct == 0 && q == 0) nv.x = od.x;   // c==0 frozen
      *(float4*)(sout + base) = nv;
    }
  }
}

// ---------- final f32 state -> output (dtype per flag) ----------
__global__ __launch_bounds__(256) void nca_out(const float* __restrict__ st,
                                               void* __restrict__ out,
                                               const uint32_t* __restrict__ flagp) {
  uint32_t bf = *flagp;
  int gid = blockIdx.x * 256 + threadIdx.x;
  float4 v = *(const float4*)(st + (size_t)gid * 4);
  if (bf) {
    ushort4 u;
    u.x = f2bf(v.x); u.y = f2bf(v.y); u.z = f2bf(v.z); u.w = f2bf(v.w);
    *(ushort4*)((ushort_t*)out + (size_t)gid * 4) = u;
  } else {
    *(float4*)((float*)out + (size_t)gid * 4) = v;
  }
}

extern "C" void kernel_launch(void* const* d_in, const int* in_sizes, int n_in,
                              void* d_out, int out_size, void* d_ws, size_t ws_size,
                              hipStream_t stream) {
  float* ws = (float*)d_ws;
  float* sA = ws;
  float* sB = ws + NSTATE;
  float* wb = ws + 2 * NSTATE;
  ushort_t* wh = (ushort_t*)(ws + 2 * NSTATE + WB_TOT);
  uint32_t* flag = (uint32_t*)(ws + 2 * NSTATE + WB_TOT + WH_TOT / 2);

  nca_detect<<<1, 256, 0, stream>>>((const uint32_t*)d_in[0], flag);
  nca_prep<<<77, 256, 0, stream>>>(d_in[1], d_in[2], d_in[3], d_in[4], d_in[5],
                                   wb, wh, flag);
  nca_init<<<NVOX / 256, 256, 0, stream>>>(d_in[0], sA, flag);

  float* src = sA;
  float* dst = sB;
  for (int s = 0; s < 10; s++) {
    uint32_t o0, o1;
    tf2x32(0u, 42u, 0u, (uint32_t)s, o0, o1);   // folded step key, host-side
    nca_step<<<864, 256, 0, stream>>>(src, dst, wb, wh, o0, o1);
    float* tmp = src; src = dst; dst = tmp;
  }
  nca_out<<<NSTATE / 4 / 256, 256, 0, stream>>>(src, d_out, flag);
}

// Round 10
// 483.282 us; speedup vs baseline: 5.9027x; 1.0240x over previous
//
#include <hip/hip_runtime.h>
#include <stdint.h>

typedef unsigned short ushort_t;

// Problem constants
#define NVOX   221184      // 2*48*48*48 voxels
#define NSTATE 7077888     // NVOX * 32 channels
// ws layout: stateA f32 | stateB f32 | wb f32 (biases) | wh u16 (bf16 frag tables) | flag
#define WB_CB   0          // conv_b[16]
#define WB_F0B  16         // fc0_b[128]
#define WB_TOT  160
// wh offsets (u16 units): pre-swizzled hi/lo bf16 fragment tables (R8/R9-verified)
#define CWH 0              // conv W frags [14 kst][64 lane][8]
#define CWL 7168
#define B0H 14336          // fc0 W frags [2 kst][8 nt][64][8]
#define B0L 22528
#define B1H 30720          // fc1 W frags [4 kt][2 ct][64][8]
#define B1L 34816
#define WH_TOT 38912       // u16

// LDS (u16 units) — 38 KB total (+1 KB maskb) -> 4 blocks/CU by LDS
#define XC0   0            // halo xc: 600 rows x 24 (16 ch + pad8; 48B rows, b128-aligned)
#define CVS0  14400        // cv scratch: 4 waves x 16 x 24
#define HS0   15936        // h scratch: 4 waves x (2 halves x 16 x 24) = 768 u16/wave
#define SH_TOT 19008       // u16 = 38016 B

typedef __attribute__((ext_vector_type(8))) short    s8v;    // 8 bf16 (4 VGPRs)
typedef __attribute__((ext_vector_type(4))) float    f32x4;  // MFMA C/D
typedef __attribute__((ext_vector_type(4))) ushort_t u16x4;  // 8B LDS chunk
union AF { s8v v; u16x4 h[2]; ushort_t u[8]; };
#define MFMA(a,b,c) __builtin_amdgcn_mfma_f32_16x16x32_bf16((a),(b),(c),0,0,0)
// compiler-only memory barrier: same-wave DS ops are HW-in-order (R9-verified pattern)
#define CBAR() __asm__ volatile("" ::: "memory")

// ---------- bf16 helpers ----------
__host__ __device__ __forceinline__ float bf2f(ushort_t u) {
  union { uint32_t u; float f; } v; v.u = ((uint32_t)u) << 16; return v.f;
}
__device__ __forceinline__ ushort_t f2bf(float f) {  // RNE, finite values
  union { float f; uint32_t u; } v; v.f = f;
  uint32_t r = (v.u + 0x7FFFu + ((v.u >> 16) & 1u)) >> 16;
  return (ushort_t)r;
}
__device__ __forceinline__ float ldin(const void* p, int i, uint32_t bf) {
  return bf ? bf2f(((const ushort_t*)p)[i]) : ((const float*)p)[i];
}

// ---------- JAX Threefry-2x32 (verified bit-exact R3) ----------
__host__ __device__ __forceinline__ void tf2x32(uint32_t k0, uint32_t k1,
                                                uint32_t x0, uint32_t x1,
                                                uint32_t& o0, uint32_t& o1) {
  uint32_t ks2 = k0 ^ k1 ^ 0x1BD11BDAu;
#define TFR(r) { x0 += x1; x1 = (x1 << r) | (x1 >> (32 - r)); x1 ^= x0; }
  x0 += k0; x1 += k1;
  TFR(13) TFR(15) TFR(26) TFR(6)
  x0 += k1;  x1 += ks2 + 1u;
  TFR(17) TFR(29) TFR(16) TFR(24)
  x0 += ks2; x1 += k0 + 2u;
  TFR(13) TFR(15) TFR(26) TFR(6)
  x0 += k0;  x1 += k1 + 3u;
  TFR(17) TFR(29) TFR(16) TFR(24)
  x0 += k1;  x1 += ks2 + 4u;
  TFR(13) TFR(15) TFR(26) TFR(6)
  x0 += ks2; x1 += k0 + 5u;
#undef TFR
  o0 = x0; o1 = x1;
}
__device__ __forceinline__ float mask_val(uint32_t k0, uint32_t k1, uint32_t vi) {
  uint32_t r0, r1;
  tf2x32(k0, k1, 0u, vi, r0, r1);
  uint32_t bits = r0 ^ r1;
  return ((bits >> 9) > 0x400000u) ? 1.0f : 0.0f;
}

// ---------- dtype detector (verified R3: flags f32) ----------
__global__ void nca_detect(const uint32_t* __restrict__ x, uint32_t* __restrict__ flag) {
  __shared__ int cnt[256];
  uint32_t w = x[threadIdx.x];
  uint32_t e = (w >> 7) & 0xFFu;
  cnt[threadIdx.x] = (e >= 110u && e <= 140u) ? 1 : 0;
  __syncthreads();
  for (int s = 128; s > 0; s >>= 1) {
    if ((int)threadIdx.x < s) cnt[threadIdx.x] += cnt[threadIdx.x + s];
    __syncthreads();
  }
  if (threadIdx.x == 0) *flag = (cnt[0] >= 160) ? 1u : 0u;
}

// ---------- weight prep (VERBATIM from R8/R9 — verified) ----------
__global__ __launch_bounds__(256) void nca_prep(
    const void* __restrict__ cw, const void* __restrict__ cb,
    const void* __restrict__ f0w, const void* __restrict__ f0b,
    const void* __restrict__ f1w, float* __restrict__ wb,
    ushort_t* __restrict__ wh, const uint32_t* __restrict__ flagp) {
  uint32_t bf = *flagp;
  int e = blockIdx.x * 256 + threadIdx.x;
  if (e < 16) { wb[WB_CB + e] = ldin(cb, e, bf); return; }
  if (e < 144) { wb[WB_F0B + (e - 16)] = ldin(f0b, e - 16, bf); return; }
  int eh = e - 144;
  if (eh >= 19456) return;
  float v; int hidx, lidx;
  if (eh < 7168) {
    int kst = eh >> 9; int l = (eh >> 3) & 63; int j = eh & 7;
    int qq = l >> 4; int o = l & 15;
    int t = kst * 2 + (qq >> 1); int i = (qq & 1) * 8 + j;
    v = (t <= 26) ? ldin(cw, o * 432 + i * 27 + t, bf) : 0.0f;
    hidx = CWH + eh; lidx = CWL + eh;
  } else if (eh < 15360) {
    int r = eh - 7168;
    int kst = r >> 12; int rem = r & 4095;
    int nt = rem >> 9; int l = (rem >> 3) & 63; int j = rem & 7;
    int qq = l >> 4; int n = nt * 16 + (l & 15);
    int k = kst * 32 + qq * 8 + j;
    v = (k < 48) ? ldin(f0w, n * 48 + k, bf) : 0.0f;
    hidx = B0H + r; lidx = B0L + r;
  } else {
    int r = eh - 15360;
    int kt = r >> 10; int rem = r & 1023;
    int n2 = rem >> 9; int l = (rem >> 3) & 63; int j = rem & 7;
    int qq = l >> 4; int c = n2 * 16 + (l & 15);
    int k = kt * 32 + qq * 8 + j;
    v = ldin(f1w, c * 128 + k, bf);
    hidx = B1H + r; lidx = B1L + r;
  }
  ushort_t hi = f2bf(v);
  float hf = bf2f(hi);
  ushort_t lo = f2bf(v - hf);
  wh[hidx] = hi; wh[lidx] = lo;
}

// ---------- init: state ch0..15 = x, ch16..31 = 0 ----------
__global__ __launch_bounds__(256) void nca_init(const void* __restrict__ x,
                                                float* __restrict__ st,
                                                const uint32_t* __restrict__ flagp) {
  uint32_t bf = *flagp;
  int gid = blockIdx.x * 256 + threadIdx.x;
  float v[32];
#pragma unroll
  for (int c = 0; c < 16; c++) v[c] = ldin(x, gid * 16 + c, bf);
#pragma unroll
  for (int c = 16; c < 32; c++) v[c] = 0.0f;
  float* po = st + (size_t)gid * 32;
#pragma unroll
  for (int c = 0; c < 32; c += 4)
    *(float4*)(po + c) = make_float4(v[c], v[c + 1], v[c + 2], v[c + 3]);
}

// ---------- one NCA step, MFMA v3 ----------
// v2 (R9) + occupancy/pipelining: LDS 53.8->39.0 KB (small per-wave h scratch:
// each lane's fc1 fragment comes from exactly one t2 half since k=q*8+j spans
// one 16-block -> per-mm write 2 halves, read one b128 selected by q>>1);
// launch_bounds(256,3) (~170 VGPR cap fits ~160 live set — avoids R5 spill trap);
// conv kst / fc kt loops fully unrolled so weight-frag loads issue ahead.
__global__ __launch_bounds__(256, 3) void nca_step(
    const float* __restrict__ sin, float* __restrict__ sout,
    const float* __restrict__ wb, const ushort_t* __restrict__ wh,
    uint32_t k0, uint32_t k1) {
  __shared__ ushort_t SH[SH_TOT];
  __shared__ float maskb[256];

  int bx = blockIdx.x;
  int tx = bx % 6;  int r0i = bx / 6;
  int ty = r0i % 6; int r1i = r0i / 6;
  int tz = r1i % 12; int b = r1i / 12;
  int tid = threadIdx.x;

  // ---- Phase A: halo xc -> LDS bf16 (48B rows); masks ----
  for (int hr = tid; hr < 600; hr += 256) {
    int hz = hr / 100, rm = hr % 100, hy = rm / 10, hx = rm % 10;
    int gd = tz * 4 + hz - 1; gd = (gd < 0) ? 1 : ((gd > 47) ? 46 : gd);
    int gh = ty * 8 + hy - 1; gh = (gh < 0) ? 1 : ((gh > 47) ? 46 : gh);
    int gw = tx * 8 + hx - 1; gw = (gw < 0) ? 1 : ((gw > 47) ? 46 : gw);
    const float* p = sin + ((((size_t)b * 48 + gd) * 48 + gh) * 48 + gw) * 32;
    ushort_t* dst = SH + XC0 + hr * 24;
#pragma unroll
    for (int c = 0; c < 16; c += 4) {
      float4 v = *(const float4*)(p + c);
      u16x4 t;
      t[0] = f2bf(v.x); t[1] = f2bf(v.y); t[2] = f2bf(v.z); t[3] = f2bf(v.w);
      *(u16x4*)(dst + c) = t;
    }
  }
  {
    int v = tid; int x = v & 7, y = (v >> 3) & 7, z = v >> 6;
    int gid = ((b * 48 + tz * 4 + z) * 48 + ty * 8 + y) * 48 + tx * 8 + x;
    maskb[v] = mask_val(k0, k1, (uint32_t)gid);
  }
  __syncthreads();   // the ONLY block barrier

  int lane = tid & 63, wave = tid >> 6;
  int q = lane >> 4, mcol = lane & 15;
  int ql = q & 1, qh = q >> 1;
  const int cvs = CVS0 + wave * 384;
  const int hs  = HS0 + wave * 768;     // two 384-u16 halves

  // lane's column-voxel geometry per m-tile
  int hb[4]; int gvx[4];
#pragma unroll
  for (int mm = 0; mm < 4; mm++) {
    int v = (wave * 4 + mm) * 16 + mcol;
    int x = v & 7, y = (v >> 3) & 7, z = v >> 6;
    hb[mm] = (z + 1) * 100 + (y + 1) * 10 + (x + 1);
    gvx[mm] = ((b * 48 + tz * 4 + z) * 48 + ty * 8 + y) * 48 + tx * 8 + x;
  }

  // ---- conv: cv^T[o][v], kst outer (weights once), mm inner; FULL UNROLL ----
  f32x4 acc[4];
#pragma unroll
  for (int mm = 0; mm < 4; mm++) acc[mm] = (f32x4){0.f, 0.f, 0.f, 0.f};
#pragma unroll
  for (int kst = 0; kst < 14; kst++) {
    int t = kst * 2 + qh; if (t > 26) t = 26;     // padded taps hit zero weights
    int kz = t % 3, kxx = t / 9, kyy = (t / 3) % 3;
    int roff = (kz - 1) * 100 + (kxx - 1) * 10 + (kyy - 1);
    s8v bh = *(const s8v*)(wh + CWH + (size_t)(kst * 64 + lane) * 8);
    s8v bl = *(const s8v*)(wh + CWL + (size_t)(kst * 64 + lane) * 8);
#pragma unroll
    for (int mm = 0; mm < 4; mm++) {
      s8v a = *(const s8v*)(SH + (hb[mm] + roff) * 24 + ql * 8);
      acc[mm] = MFMA(bh, a, acc[mm]);
      acc[mm] = MFMA(bl, a, acc[mm]);
    }
  }

  // ---- din B-frags: k0 = [xc(0..15) | cv(16..31)], k1 = [xm(32..47) | 0] ----
  float4 cb4 = *(const float4*)(wb + WB_CB + q * 4);
  AF fk0[4], fk1[4];
#pragma unroll
  for (int mm = 0; mm < 4; mm++) {
    u16x4 pk;
    pk[0] = f2bf(acc[mm][0] + cb4.x);
    pk[1] = f2bf(acc[mm][1] + cb4.y);
    pk[2] = f2bf(acc[mm][2] + cb4.z);
    pk[3] = f2bf(acc[mm][3] + cb4.w);
    *(u16x4*)(SH + cvs + mcol * 24 + q * 4) = pk;   // cv^T -> [voxel][o] rows
    CBAR();
    int off0 = (q < 2) ? (hb[mm] * 24 + q * 8)                 // xc: center-tap halo row
                       : (cvs + mcol * 24 + (q - 2) * 8);      // cv
    fk0[mm].v = *(const s8v*)(SH + off0);
    CBAR();                                          // keep next mm's write after read
    if (q < 2) {
      const float* pm = sin + (size_t)gvx[mm] * 32 + 16 + q * 8;
      float4 m0 = *(const float4*)(pm);
      float4 m1 = *(const float4*)(pm + 4);
      fk1[mm].u[0] = f2bf(m0.x); fk1[mm].u[1] = f2bf(m0.y);
      fk1[mm].u[2] = f2bf(m0.z); fk1[mm].u[3] = f2bf(m0.w);
      fk1[mm].u[4] = f2bf(m1.x); fk1[mm].u[5] = f2bf(m1.y);
      fk1[mm].u[6] = f2bf(m1.z); fk1[mm].u[7] = f2bf(m1.w);
    } else {
#pragma unroll
      for (int j = 0; j < 8; j++) fk1[mm].u[j] = 0;
    }
  }

  // ---- fc0 (h^T) + fc1 (dx^T): kt outer (weights hoisted), mm inner ----
  f32x4 dxa[4][2];
#pragma unroll
  for (int mm = 0; mm < 4; mm++) {
    dxa[mm][0] = (f32x4){0.f, 0.f, 0.f, 0.f};
    dxa[mm][1] = (f32x4){0.f, 0.f, 0.f, 0.f};
  }
#pragma unroll
  for (int kt = 0; kt < 4; kt++) {
    int nt0 = kt * 2, nt1 = kt * 2 + 1;
    s8v w1h0 = *(const s8v*)(wh + B1H + (size_t)((nt0) * 64 + lane) * 8);
    s8v w1l0 = *(const s8v*)(wh + B1L + (size_t)((nt0) * 64 + lane) * 8);
    s8v w1h1 = *(const s8v*)(wh + B1H + (size_t)((nt1) * 64 + lane) * 8);
    s8v w1l1 = *(const s8v*)(wh + B1L + (size_t)((nt1) * 64 + lane) * 8);
    s8v f0h00 = *(const s8v*)(wh + B0H + (size_t)((nt0) * 64 + lane) * 8);     // t2=0,kst0
    s8v f0l00 = *(const s8v*)(wh + B0L + (size_t)((nt0) * 64 + lane) * 8);
    s8v f0h01 = *(const s8v*)(wh + B0H + (size_t)((8 + nt0) * 64 + lane) * 8); // t2=0,kst1
    s8v f0l01 = *(const s8v*)(wh + B0L + (size_t)((8 + nt0) * 64 + lane) * 8);
    s8v f0h10 = *(const s8v*)(wh + B0H + (size_t)((nt1) * 64 + lane) * 8);     // t2=1,kst0
    s8v f0l10 = *(const s8v*)(wh + B0L + (size_t)((nt1) * 64 + lane) * 8);
    s8v f0h11 = *(const s8v*)(wh + B0H + (size_t)((8 + nt1) * 64 + lane) * 8); // t2=1,kst1
    s8v f0l11 = *(const s8v*)(wh + B0L + (size_t)((8 + nt1) * 64 + lane) * 8);
    float4 b40 = *(const float4*)(wb + WB_F0B + nt0 * 16 + q * 4);
    float4 b41 = *(const float4*)(wb + WB_F0B + nt1 * 16 + q * 4);
#pragma unroll
    for (int mm = 0; mm < 4; mm++) {
      f32x4 a0 = (f32x4){b40.x, b40.y, b40.z, b40.w};
      a0 = MFMA(f0h00, fk0[mm].v, a0);
      a0 = MFMA(f0l00, fk0[mm].v, a0);
      a0 = MFMA(f0h01, fk1[mm].v, a0);
      a0 = MFMA(f0l01, fk1[mm].v, a0);
      f32x4 a1 = (f32x4){b41.x, b41.y, b41.z, b41.w};
      a1 = MFMA(f0h10, fk0[mm].v, a1);
      a1 = MFMA(f0l10, fk0[mm].v, a1);
      a1 = MFMA(f0h11, fk1[mm].v, a1);
      a1 = MFMA(f0l11, fk1[mm].v, a1);
      u16x4 p0, p1;
      p0[0] = f2bf(fmaxf(a0[0], 0.f)); p0[1] = f2bf(fmaxf(a0[1], 0.f));
      p0[2] = f2bf(fmaxf(a0[2], 0.f)); p0[3] = f2bf(fmaxf(a0[3], 0.f));
      p1[0] = f2bf(fmaxf(a1[0], 0.f)); p1[1] = f2bf(fmaxf(a1[1], 0.f));
      p1[2] = f2bf(fmaxf(a1[2], 0.f)); p1[3] = f2bf(fmaxf(a1[3], 0.f));
      *(u16x4*)(SH + hs + mcol * 24 + q * 4) = p0;          // half0 (t2=0)
      *(u16x4*)(SH + hs + 384 + mcol * 24 + q * 4) = p1;    // half1 (t2=1)
      CBAR();
      // a2 frag: k = kt*32 + q*8 + j -> entirely in half (q>>1), n' = (q&1)*8 + j
      s8v a2 = *(const s8v*)(SH + hs + (q >> 1) * 384 + mcol * 24 + (q & 1) * 8);
      CBAR();                                               // order next mm's writes
      dxa[mm][0] = MFMA(w1h0, a2, dxa[mm][0]);
      dxa[mm][0] = MFMA(w1l0, a2, dxa[mm][0]);
      dxa[mm][1] = MFMA(w1h1, a2, dxa[mm][1]);
      dxa[mm][1] = MFMA(w1l1, a2, dxa[mm][1]);
    }
  }

  // ---- epilogue: coalesced float4 residual update; channel 0 frozen ----
#pragma unroll
  for (int mm = 0; mm < 4; mm++) {
    float mk = maskb[wave * 64 + mm * 16 + mcol];
#pragma unroll
    for (int ct = 0; ct < 2; ct++) {
      size_t base = (size_t)gvx[mm] * 32 + ct * 16 + q * 4;
      float4 od = *(const float4*)(sin + base);
      float4 nv;
      nv.x = fmaf(dxa[mm][ct][0], mk, od.x);
      nv.y = fmaf(dxa[mm][ct][1], mk, od.y);
      nv.z = fmaf(dxa[mm][ct][2], mk, od.z);
      nv.w = fmaf(dxa[mm][ct][3], mk, od.w);
      if (ct == 0 && q == 0) nv.x = od.x;   // c==0 frozen
      *(float4*)(sout + base) = nv;
    }
  }
}

// ---------- final f32 state -> output (dtype per flag) ----------
__global__ __launch_bounds__(256) void nca_out(const float* __restrict__ st,
                                               void* __restrict__ out,
                                               const uint32_t* __restrict__ flagp) {
  uint32_t bf = *flagp;
  int gid = blockIdx.x * 256 + threadIdx.x;
  float4 v = *(const float4*)(st + (size_t)gid * 4);
  if (bf) {
    ushort4 u;
    u.x = f2bf(v.x); u.y = f2bf(v.y); u.z = f2bf(v.z); u.w = f2bf(v.w);
    *(ushort4*)((ushort_t*)out + (size_t)gid * 4) = u;
  } else {
    *(float4*)((float*)out + (size_t)gid * 4) = v;
  }
}

extern "C" void kernel_launch(void* const* d_in, const int* in_sizes, int n_in,
                              void* d_out, int out_size, void* d_ws, size_t ws_size,
                              hipStream_t stream) {
  float* ws = (float*)d_ws;
  float* sA = ws;
  float* sB = ws + NSTATE;
  float* wb = ws + 2 * NSTATE;
  ushort_t* wh = (ushort_t*)(ws + 2 * NSTATE + WB_TOT);
  uint32_t* flag = (uint32_t*)(ws + 2 * NSTATE + WB_TOT + WH_TOT / 2);

  nca_detect<<<1, 256, 0, stream>>>((const uint32_t*)d_in[0], flag);
  nca_prep<<<77, 256, 0, stream>>>(d_in[1], d_in[2], d_in[3], d_in[4], d_in[5],
                                   wb, wh, flag);
  nca_init<<<NVOX / 256, 256, 0, stream>>>(d_in[0], sA, flag);

  float* src = sA;
  float* dst = sB;
  for (int s = 0; s < 10; s++) {
    uint32_t o0, o1;
    tf2x32(0u, 42u, 0u, (uint32_t)s, o0, o1);   // folded step key, host-side
    nca_step<<<864, 256, 0, stream>>>(src, dst, wb, wh, o0, o1);
    float* tmp = src; src = dst; dst = tmp;
  }
  nca_out<<<NSTATE / 4 / 256, 256, 0, stream>>>(src, d_out, flag);
}

// Round 11
// 392.734 us; speedup vs baseline: 7.2637x; 1.2306x over previous
//
#include <hip/hip_runtime.h>
#include <stdint.h>

typedef unsigned short ushort_t;

// Problem constants
#define NVOX   221184      // 2*48*48*48 voxels
#define NSTATE 7077888     // NVOX * 32 channels
// ws layout: stateA bf16 | stateB bf16 | wb f32 (biases) | wh u16 (frag tables) | flag
#define WB_CB   0          // conv_b[16]
#define WB_F0B  16         // fc0_b[128]
#define WB_TOT  160
// wh offsets (u16 units): pre-swizzled hi/lo bf16 fragment tables (R8/R9-verified)
#define CWH 0              // conv W frags [14 kst][64 lane][8]
#define CWL 7168
#define B0H 14336          // fc0 W frags [2 kst][8 nt][64][8]
#define B0L 22528
#define B1H 30720          // fc1 W frags [4 kt][2 ct][64][8]
#define B1L 34816
#define WH_TOT 38912       // u16

// LDS (u16 units) — 38 KB total (+1 KB maskb)
#define XC0   0            // halo xc: 600 rows x 24 (16 ch + pad8; 48B rows, b128-aligned)
#define CVS0  14400        // cv scratch: 4 waves x 16 x 24
#define HS0   15936        // h scratch: 4 waves x (2 halves x 16 x 24) = 768 u16/wave
#define SH_TOT 19008       // u16 = 38016 B

typedef __attribute__((ext_vector_type(8))) short    s8v;    // 8 bf16 (4 VGPRs)
typedef __attribute__((ext_vector_type(4))) float    f32x4;  // MFMA C/D
typedef __attribute__((ext_vector_type(4))) ushort_t u16x4;  // 8B chunk
union AF { s8v v; u16x4 h[2]; ushort_t u[8]; };
#define MFMA(a,b,c) __builtin_amdgcn_mfma_f32_16x16x32_bf16((a),(b),(c),0,0,0)
// compiler-only memory barrier: same-wave DS ops are HW-in-order (R9/R10-verified pattern)
#define CBAR() __asm__ volatile("" ::: "memory")

// ---------- bf16 helpers ----------
__host__ __device__ __forceinline__ float bf2f(ushort_t u) {
  union { uint32_t u; float f; } v; v.u = ((uint32_t)u) << 16; return v.f;
}
__device__ __forceinline__ ushort_t f2bf(float f) {  // RNE, finite values
  union { float f; uint32_t u; } v; v.f = f;
  uint32_t r = (v.u + 0x7FFFu + ((v.u >> 16) & 1u)) >> 16;
  return (ushort_t)r;
}
__device__ __forceinline__ float ldin(const void* p, int i, uint32_t bf) {
  return bf ? bf2f(((const ushort_t*)p)[i]) : ((const float*)p)[i];
}

// ---------- JAX Threefry-2x32 (verified bit-exact R3) ----------
__host__ __device__ __forceinline__ void tf2x32(uint32_t k0, uint32_t k1,
                                                uint32_t x0, uint32_t x1,
                                                uint32_t& o0, uint32_t& o1) {
  uint32_t ks2 = k0 ^ k1 ^ 0x1BD11BDAu;
#define TFR(r) { x0 += x1; x1 = (x1 << r) | (x1 >> (32 - r)); x1 ^= x0; }
  x0 += k0; x1 += k1;
  TFR(13) TFR(15) TFR(26) TFR(6)
  x0 += k1;  x1 += ks2 + 1u;
  TFR(17) TFR(29) TFR(16) TFR(24)
  x0 += ks2; x1 += k0 + 2u;
  TFR(13) TFR(15) TFR(26) TFR(6)
  x0 += k0;  x1 += k1 + 3u;
  TFR(17) TFR(29) TFR(16) TFR(24)
  x0 += k1;  x1 += ks2 + 4u;
  TFR(13) TFR(15) TFR(26) TFR(6)
  x0 += ks2; x1 += k0 + 5u;
#undef TFR
  o0 = x0; o1 = x1;
}
__device__ __forceinline__ float mask_val(uint32_t k0, uint32_t k1, uint32_t vi) {
  uint32_t r0, r1;
  tf2x32(k0, k1, 0u, vi, r0, r1);
  uint32_t bits = r0 ^ r1;
  return ((bits >> 9) > 0x400000u) ? 1.0f : 0.0f;
}

// ---------- dtype detector (verified R3: flags f32) ----------
__global__ void nca_detect(const uint32_t* __restrict__ x, uint32_t* __restrict__ flag) {
  __shared__ int cnt[256];
  uint32_t w = x[threadIdx.x];
  uint32_t e = (w >> 7) & 0xFFu;
  cnt[threadIdx.x] = (e >= 110u && e <= 140u) ? 1 : 0;
  __syncthreads();
  for (int s = 128; s > 0; s >>= 1) {
    if ((int)threadIdx.x < s) cnt[threadIdx.x] += cnt[threadIdx.x + s];
    __syncthreads();
  }
  if (threadIdx.x == 0) *flag = (cnt[0] >= 160) ? 1u : 0u;
}

// ---------- weight prep (VERBATIM from R8/R9 — verified) ----------
__global__ __launch_bounds__(256) void nca_prep(
    const void* __restrict__ cw, const void* __restrict__ cb,
    const void* __restrict__ f0w, const void* __restrict__ f0b,
    const void* __restrict__ f1w, float* __restrict__ wb,
    ushort_t* __restrict__ wh, const uint32_t* __restrict__ flagp) {
  uint32_t bf = *flagp;
  int e = blockIdx.x * 256 + threadIdx.x;
  if (e < 16) { wb[WB_CB + e] = ldin(cb, e, bf); return; }
  if (e < 144) { wb[WB_F0B + (e - 16)] = ldin(f0b, e - 16, bf); return; }
  int eh = e - 144;
  if (eh >= 19456) return;
  float v; int hidx, lidx;
  if (eh < 7168) {
    int kst = eh >> 9; int l = (eh >> 3) & 63; int j = eh & 7;
    int qq = l >> 4; int o = l & 15;
    int t = kst * 2 + (qq >> 1); int i = (qq & 1) * 8 + j;
    v = (t <= 26) ? ldin(cw, o * 432 + i * 27 + t, bf) : 0.0f;
    hidx = CWH + eh; lidx = CWL + eh;
  } else if (eh < 15360) {
    int r = eh - 7168;
    int kst = r >> 12; int rem = r & 4095;
    int nt = rem >> 9; int l = (rem >> 3) & 63; int j = rem & 7;
    int qq = l >> 4; int n = nt * 16 + (l & 15);
    int k = kst * 32 + qq * 8 + j;
    v = (k < 48) ? ldin(f0w, n * 48 + k, bf) : 0.0f;
    hidx = B0H + r; lidx = B0L + r;
  } else {
    int r = eh - 15360;
    int kt = r >> 10; int rem = r & 1023;
    int n2 = rem >> 9; int l = (rem >> 3) & 63; int j = rem & 7;
    int qq = l >> 4; int c = n2 * 16 + (l & 15);
    int k = kt * 32 + qq * 8 + j;
    v = ldin(f1w, c * 128 + k, bf);
    hidx = B1H + r; lidx = B1L + r;
  }
  ushort_t hi = f2bf(v);
  float hf = bf2f(hi);
  ushort_t lo = f2bf(v - hf);
  wh[hidx] = hi; wh[lidx] = lo;
}

// ---------- init: bf16 state; ch0..15 = x, ch16..31 = 0 ----------
__global__ __launch_bounds__(256) void nca_init(const void* __restrict__ x,
                                                ushort_t* __restrict__ st,
                                                const uint32_t* __restrict__ flagp) {
  uint32_t bf = *flagp;
  int gid = blockIdx.x * 256 + threadIdx.x;
  ushort_t* po = st + (size_t)gid * 32;
  if (bf) {
    const ushort_t* xs = (const ushort_t*)x + (size_t)gid * 16;
    *(uint4*)(po)     = *(const uint4*)(xs);
    *(uint4*)(po + 8) = *(const uint4*)(xs + 8);
  } else {
    const float* xs = (const float*)x + (size_t)gid * 16;
#pragma unroll
    for (int c = 0; c < 16; c += 4) {
      float4 v = *(const float4*)(xs + c);
      u16x4 t;
      t[0] = f2bf(v.x); t[1] = f2bf(v.y); t[2] = f2bf(v.z); t[3] = f2bf(v.w);
      *(u16x4*)(po + c) = t;
    }
  }
  uint4 z = make_uint4(0, 0, 0, 0);
  *(uint4*)(po + 16) = z;
  *(uint4*)(po + 24) = z;
}

// ---------- one NCA step, MFMA v4: bf16 state ----------
// v3 + state kept bf16 between steps: Phase A = pure b128 copies (no cvt),
// xm frags = direct b128 copies, ct=0 epilogue residual from LDS halo
// (bit-identical to global), final step writes d_out per dtype flag (nca_out
// folded in). GEMM structure/tables verbatim from R8/R9 (verified).
__global__ __launch_bounds__(256, 3) void nca_step(
    const ushort_t* __restrict__ sin, ushort_t* __restrict__ sout,
    const float* __restrict__ wb, const ushort_t* __restrict__ wh,
    uint32_t k0, uint32_t k1, void* __restrict__ outp,
    const uint32_t* __restrict__ flagp, int fin) {
  __shared__ ushort_t SH[SH_TOT];
  __shared__ float maskb[256];
  uint32_t bf = *flagp;

  int bx = blockIdx.x;
  int tx = bx % 6;  int r0i = bx / 6;
  int ty = r0i % 6; int r1i = r0i / 6;
  int tz = r1i % 12; int b = r1i / 12;
  int tid = threadIdx.x;

  // ---- Phase A: halo xc -> LDS (b128 copies, no conversion); masks ----
  for (int hr = tid; hr < 600; hr += 256) {
    int hz = hr / 100, rm = hr % 100, hy = rm / 10, hx = rm % 10;
    int gd = tz * 4 + hz - 1; gd = (gd < 0) ? 1 : ((gd > 47) ? 46 : gd);
    int gh = ty * 8 + hy - 1; gh = (gh < 0) ? 1 : ((gh > 47) ? 46 : gh);
    int gw = tx * 8 + hx - 1; gw = (gw < 0) ? 1 : ((gw > 47) ? 46 : gw);
    const ushort_t* p = sin + ((((size_t)b * 48 + gd) * 48 + gh) * 48 + gw) * 32;
    ushort_t* dst = SH + XC0 + hr * 24;
    *(uint4*)(dst)     = *(const uint4*)(p);       // ch 0-7
    *(uint4*)(dst + 8) = *(const uint4*)(p + 8);   // ch 8-15
  }
  {
    int v = tid; int x = v & 7, y = (v >> 3) & 7, z = v >> 6;
    int gid = ((b * 48 + tz * 4 + z) * 48 + ty * 8 + y) * 48 + tx * 8 + x;
    maskb[v] = mask_val(k0, k1, (uint32_t)gid);
  }
  __syncthreads();   // the ONLY block barrier

  int lane = tid & 63, wave = tid >> 6;
  int q = lane >> 4, mcol = lane & 15;
  int ql = q & 1, qh = q >> 1;
  const int cvs = CVS0 + wave * 384;
  const int hs  = HS0 + wave * 768;     // two 384-u16 halves

  // lane's column-voxel geometry per m-tile
  int hb[4]; int gvx[4];
#pragma unroll
  for (int mm = 0; mm < 4; mm++) {
    int v = (wave * 4 + mm) * 16 + mcol;
    int x = v & 7, y = (v >> 3) & 7, z = v >> 6;
    hb[mm] = (z + 1) * 100 + (y + 1) * 10 + (x + 1);
    gvx[mm] = ((b * 48 + tz * 4 + z) * 48 + ty * 8 + y) * 48 + tx * 8 + x;
  }

  // ---- conv: cv^T[o][v], kst outer (weights once), mm inner; FULL UNROLL ----
  f32x4 acc[4];
#pragma unroll
  for (int mm = 0; mm < 4; mm++) acc[mm] = (f32x4){0.f, 0.f, 0.f, 0.f};
#pragma unroll
  for (int kst = 0; kst < 14; kst++) {
    int t = kst * 2 + qh; if (t > 26) t = 26;     // padded taps hit zero weights
    int kz = t % 3, kxx = t / 9, kyy = (t / 3) % 3;
    int roff = (kz - 1) * 100 + (kxx - 1) * 10 + (kyy - 1);
    s8v bh = *(const s8v*)(wh + CWH + (size_t)(kst * 64 + lane) * 8);
    s8v bl = *(const s8v*)(wh + CWL + (size_t)(kst * 64 + lane) * 8);
#pragma unroll
    for (int mm = 0; mm < 4; mm++) {
      s8v a = *(const s8v*)(SH + (hb[mm] + roff) * 24 + ql * 8);
      acc[mm] = MFMA(bh, a, acc[mm]);
      acc[mm] = MFMA(bl, a, acc[mm]);
    }
  }

  // ---- din B-frags: k0 = [xc(0..15) | cv(16..31)], k1 = [xm(32..47) | 0] ----
  float4 cb4 = *(const float4*)(wb + WB_CB + q * 4);
  AF fk0[4], fk1[4];
#pragma unroll
  for (int mm = 0; mm < 4; mm++) {
    u16x4 pk;
    pk[0] = f2bf(acc[mm][0] + cb4.x);
    pk[1] = f2bf(acc[mm][1] + cb4.y);
    pk[2] = f2bf(acc[mm][2] + cb4.z);
    pk[3] = f2bf(acc[mm][3] + cb4.w);
    *(u16x4*)(SH + cvs + mcol * 24 + q * 4) = pk;   // cv^T -> [voxel][o] rows
    CBAR();
    int off0 = (q < 2) ? (hb[mm] * 24 + q * 8)                 // xc: center-tap halo row
                       : (cvs + mcol * 24 + (q - 2) * 8);      // cv
    fk0[mm].v = *(const s8v*)(SH + off0);
    CBAR();                                          // keep next mm's write after read
    if (q < 2) {
      // xm ch 16+q*8 .. 16+q*8+7, bf16 direct (16B, aligned)
      fk1[mm].v = *(const s8v*)(sin + (size_t)gvx[mm] * 32 + 16 + q * 8);
    } else {
#pragma unroll
      for (int j = 0; j < 8; j++) fk1[mm].u[j] = 0;
    }
  }

  // ---- fc0 (h^T) + fc1 (dx^T): kt outer (weights hoisted), mm inner ----
  f32x4 dxa[4][2];
#pragma unroll
  for (int mm = 0; mm < 4; mm++) {
    dxa[mm][0] = (f32x4){0.f, 0.f, 0.f, 0.f};
    dxa[mm][1] = (f32x4){0.f, 0.f, 0.f, 0.f};
  }
#pragma unroll
  for (int kt = 0; kt < 4; kt++) {
    int nt0 = kt * 2, nt1 = kt * 2 + 1;
    s8v w1h0 = *(const s8v*)(wh + B1H + (size_t)((nt0) * 64 + lane) * 8);
    s8v w1l0 = *(const s8v*)(wh + B1L + (size_t)((nt0) * 64 + lane) * 8);
    s8v w1h1 = *(const s8v*)(wh + B1H + (size_t)((nt1) * 64 + lane) * 8);
    s8v w1l1 = *(const s8v*)(wh + B1L + (size_t)((nt1) * 64 + lane) * 8);
    s8v f0h00 = *(const s8v*)(wh + B0H + (size_t)((nt0) * 64 + lane) * 8);     // t2=0,kst0
    s8v f0l00 = *(const s8v*)(wh + B0L + (size_t)((nt0) * 64 + lane) * 8);
    s8v f0h01 = *(const s8v*)(wh + B0H + (size_t)((8 + nt0) * 64 + lane) * 8); // t2=0,kst1
    s8v f0l01 = *(const s8v*)(wh + B0L + (size_t)((8 + nt0) * 64 + lane) * 8);
    s8v f0h10 = *(const s8v*)(wh + B0H + (size_t)((nt1) * 64 + lane) * 8);     // t2=1,kst0
    s8v f0l10 = *(const s8v*)(wh + B0L + (size_t)((nt1) * 64 + lane) * 8);
    s8v f0h11 = *(const s8v*)(wh + B0H + (size_t)((8 + nt1) * 64 + lane) * 8); // t2=1,kst1
    s8v f0l11 = *(const s8v*)(wh + B0L + (size_t)((8 + nt1) * 64 + lane) * 8);
    float4 b40 = *(const float4*)(wb + WB_F0B + nt0 * 16 + q * 4);
    float4 b41 = *(const float4*)(wb + WB_F0B + nt1 * 16 + q * 4);
#pragma unroll
    for (int mm = 0; mm < 4; mm++) {
      f32x4 a0 = (f32x4){b40.x, b40.y, b40.z, b40.w};
      a0 = MFMA(f0h00, fk0[mm].v, a0);
      a0 = MFMA(f0l00, fk0[mm].v, a0);
      a0 = MFMA(f0h01, fk1[mm].v, a0);
      a0 = MFMA(f0l01, fk1[mm].v, a0);
      f32x4 a1 = (f32x4){b41.x, b41.y, b41.z, b41.w};
      a1 = MFMA(f0h10, fk0[mm].v, a1);
      a1 = MFMA(f0l10, fk0[mm].v, a1);
      a1 = MFMA(f0h11, fk1[mm].v, a1);
      a1 = MFMA(f0l11, fk1[mm].v, a1);
      u16x4 p0, p1;
      p0[0] = f2bf(fmaxf(a0[0], 0.f)); p0[1] = f2bf(fmaxf(a0[1], 0.f));
      p0[2] = f2bf(fmaxf(a0[2], 0.f)); p0[3] = f2bf(fmaxf(a0[3], 0.f));
      p1[0] = f2bf(fmaxf(a1[0], 0.f)); p1[1] = f2bf(fmaxf(a1[1], 0.f));
      p1[2] = f2bf(fmaxf(a1[2], 0.f)); p1[3] = f2bf(fmaxf(a1[3], 0.f));
      *(u16x4*)(SH + hs + mcol * 24 + q * 4) = p0;          // half0 (t2=0)
      *(u16x4*)(SH + hs + 384 + mcol * 24 + q * 4) = p1;    // half1 (t2=1)
      CBAR();
      // a2 frag: k = kt*32 + q*8 + j -> entirely in half (q>>1), n' = (q&1)*8 + j
      s8v a2 = *(const s8v*)(SH + hs + (q >> 1) * 384 + mcol * 24 + (q & 1) * 8);
      CBAR();                                               // order next mm's writes
      dxa[mm][0] = MFMA(w1h0, a2, dxa[mm][0]);
      dxa[mm][0] = MFMA(w1l0, a2, dxa[mm][0]);
      dxa[mm][1] = MFMA(w1h1, a2, dxa[mm][1]);
      dxa[mm][1] = MFMA(w1l1, a2, dxa[mm][1]);
    }
  }

  // ---- epilogue: residual + mask; ch0 frozen; bf16 state (or d_out if final) ----
#pragma unroll
  for (int mm = 0; mm < 4; mm++) {
    float mk = maskb[wave * 64 + mm * 16 + mcol];
#pragma unroll
    for (int ct = 0; ct < 2; ct++) {
      u16x4 od;
      if (ct == 0) od = *(const u16x4*)(SH + hb[mm] * 24 + q * 4);          // xc from LDS halo
      else         od = *(const u16x4*)(sin + (size_t)gvx[mm] * 32 + 16 + q * 4); // xm
      float o0 = bf2f(od[0]), o1 = bf2f(od[1]), o2 = bf2f(od[2]), o3 = bf2f(od[3]);
      float n0 = fmaf(dxa[mm][ct][0], mk, o0);
      float n1 = fmaf(dxa[mm][ct][1], mk, o1);
      float n2 = fmaf(dxa[mm][ct][2], mk, o2);
      float n3 = fmaf(dxa[mm][ct][3], mk, o3);
      if (ct == 0 && q == 0) n0 = o0;   // c==0 frozen (bit-exact copy)
      size_t off = (size_t)gvx[mm] * 32 + ct * 16 + q * 4;
      if (fin) {
        if (bf) {
          u16x4 w;
          w[0] = f2bf(n0); w[1] = f2bf(n1); w[2] = f2bf(n2); w[3] = f2bf(n3);
          *(u16x4*)((ushort_t*)outp + off) = w;
        } else {
          *(float4*)((float*)outp + off) = make_float4(n0, n1, n2, n3);
        }
      } else {
        u16x4 w;
        w[0] = f2bf(n0); w[1] = f2bf(n1); w[2] = f2bf(n2); w[3] = f2bf(n3);
        *(u16x4*)(sout + off) = w;
      }
    }
  }
}

extern "C" void kernel_launch(void* const* d_in, const int* in_sizes, int n_in,
                              void* d_out, int out_size, void* d_ws, size_t ws_size,
                              hipStream_t stream) {
  ushort_t* base = (ushort_t*)d_ws;
  ushort_t* sA = base;                       // bf16 state A
  ushort_t* sB = base + NSTATE;              // bf16 state B
  float* wb = (float*)(base + 2 * (size_t)NSTATE);
  ushort_t* wh = (ushort_t*)(wb + WB_TOT);
  uint32_t* flag = (uint32_t*)(wh + WH_TOT);

  nca_detect<<<1, 256, 0, stream>>>((const uint32_t*)d_in[0], flag);
  nca_prep<<<77, 256, 0, stream>>>(d_in[1], d_in[2], d_in[3], d_in[4], d_in[5],
                                   wb, wh, flag);
  nca_init<<<NVOX / 256, 256, 0, stream>>>(d_in[0], sA, flag);

  ushort_t* src = sA;
  ushort_t* dst = sB;
  for (int s = 0; s < 10; s++) {
    uint32_t o0, o1;
    tf2x32(0u, 42u, 0u, (uint32_t)s, o0, o1);   // folded step key, host-side
    nca_step<<<864, 256, 0, stream>>>(src, dst, wb, wh, o0, o1,
                                      d_out, flag, (s == 9) ? 1 : 0);
    ushort_t* tmp = src; src = dst; dst = tmp;
  }
}